// Round 1
// baseline (174.718 us; speedup 1.0000x reference)
//
#include <hip/hip_runtime.h>

#define BB 4096
#define TT 512
#define KK 7
#define NC 32   // chunks per sequence
#define SS 16   // steps per chunk (TT/NC)

__device__ __forceinline__ float fexp2(float x){ float r; asm("v_exp_f32 %0, %1" : "=v"(r) : "v"(x)); return r; }
__device__ __forceinline__ float flog2(float x){ float r; asm("v_log_f32 %0, %1" : "=v"(r) : "v"(x)); return r; }

// Phase 1: thread (b,c).  c==0 -> alpha vector over t=0..SS-1 (prob-space, log2 scale)
//          c>=1 -> 7x7 chunk transition matrix over t=c*SS..c*SS+SS-1
// Also accumulates the tag-path score partial and active-step count per chunk.
__global__ __launch_bounds__(256) void crf_p1(
    const float* __restrict__ em, const int* __restrict__ msk,
    const int* __restrict__ tgs, const float* __restrict__ trn,
    const float* __restrict__ stt,
    float* __restrict__ wsA, float* __restrict__ wsP,
    float* __restrict__ wsS, int* __restrict__ wsC)
{
  const float L2E = 1.44269504088896340736f;
  int tid = blockIdx.x * 256 + threadIdx.x;
  int c = tid >> 12;        // BB = 4096 = 2^12
  int b = tid & (BB - 1);

  // exp2 of (scaled) transitions, reused every step
  float e2[KK*KK];
  #pragma unroll
  for (int i = 0; i < KK*KK; i++) e2[i] = fexp2(trn[i] * L2E);

  float sc = 0.f; int cnt = 0;
  const size_t ebase = (size_t)b * TT * KK;

  if (c == 0) {
    // ---- alpha-vector chunk ----
    float u[KK], Ls;
    float a2[KK];
    #pragma unroll
    for (int j = 0; j < KK; j++) a2[j] = (stt[j] + em[ebase + j]) * L2E;
    float m = a2[0];
    #pragma unroll
    for (int j = 1; j < KK; j++) m = fmaxf(m, a2[j]);
    #pragma unroll
    for (int j = 0; j < KK; j++) u[j] = fexp2(a2[j] - m);
    Ls = m;
    cnt = msk[b * TT];               // mask[b][0] (always 1 here)
    int tprev = tgs[b * TT];
    // prefetch t=1
    float en_[KK]; int mkn, tgn;
    #pragma unroll
    for (int k = 0; k < KK; k++) en_[k] = em[ebase + KK + k];
    mkn = msk[b * TT + 1]; tgn = tgs[b * TT + 1];

    for (int t = 1; t < SS; ++t) {
      float e_[KK];
      #pragma unroll
      for (int k = 0; k < KK; k++) e_[k] = en_[k];
      int mk = mkn, tg = tgn;
      if (!mk) break;
      int t2 = (t + 1 < TT) ? t + 1 : TT - 1;
      #pragma unroll
      for (int k = 0; k < KK; k++) en_[k] = em[ebase + (size_t)t2 * KK + k];
      mkn = msk[b * TT + t2]; tgn = tgs[b * TT + t2];
      // score partial: trans[tprev][tg] + em[t][tg]
      float es = e_[0];
      #pragma unroll
      for (int k = 1; k < KK; k++) es = (tg == k) ? e_[k] : es;
      sc += trn[tprev * KK + tg] + es;
      tprev = tg; cnt++;
      // u' = (u @ E2) * 2^em
      float g[KK];
      #pragma unroll
      for (int j = 0; j < KK; j++) g[j] = fexp2(e_[j] * L2E);
      float acc[KK];
      #pragma unroll
      for (int j = 0; j < KK; j++) acc[j] = u[0] * e2[j];
      #pragma unroll
      for (int k = 1; k < KK; k++)
        #pragma unroll
        for (int j = 0; j < KK; j++) acc[j] = fmaf(u[k], e2[k*KK + j], acc[j]);
      #pragma unroll
      for (int j = 0; j < KK; j++) u[j] = acc[j] * g[j];
      if ((cnt & 3) == 0) {          // exact pow2 renorm
        float mm = u[0];
        #pragma unroll
        for (int j = 1; j < KK; j++) mm = fmaxf(mm, u[j]);
        int ex = (int)((__float_as_uint(mm) >> 23) & 255) - 127;
        float scl = __uint_as_float((unsigned)(127 - ex) << 23);
        Ls += (float)ex;
        #pragma unroll
        for (int j = 0; j < KK; j++) u[j] *= scl;
      }
    }
    #pragma unroll
    for (int j = 0; j < KK; j++) wsA[b * 8 + j] = Ls + flog2(u[j]);
    wsS[b] = sc; wsC[b] = cnt;
  } else {
    // ---- matrix chunk ----
    int t0 = c * SS;
    float R[KK*KK], Lr[KK];
    #pragma unroll
    for (int i = 0; i < KK*KK; i++) R[i] = 0.f;
    #pragma unroll
    for (int i = 0; i < KK; i++) { R[i*KK + i] = 1.f; Lr[i] = 0.f; }
    int tprev = tgs[b * TT + t0 - 1];
    float en_[KK]; int mkn, tgn;
    #pragma unroll
    for (int k = 0; k < KK; k++) en_[k] = em[ebase + (size_t)t0 * KK + k];
    mkn = msk[b * TT + t0]; tgn = tgs[b * TT + t0];

    for (int t = t0; t < t0 + SS; ++t) {
      float e_[KK];
      #pragma unroll
      for (int k = 0; k < KK; k++) e_[k] = en_[k];
      int mk = mkn, tg = tgn;
      if (!mk) break;
      int t2 = (t + 1 < TT) ? t + 1 : TT - 1;
      #pragma unroll
      for (int k = 0; k < KK; k++) en_[k] = em[ebase + (size_t)t2 * KK + k];
      mkn = msk[b * TT + t2]; tgn = tgs[b * TT + t2];
      float es = e_[0];
      #pragma unroll
      for (int k = 1; k < KK; k++) es = (tg == k) ? e_[k] : es;
      sc += trn[tprev * KK + tg] + es;
      tprev = tg; cnt++;
      float g[KK];
      #pragma unroll
      for (int j = 0; j < KK; j++) g[j] = fexp2(e_[j] * L2E);
      #pragma unroll
      for (int i = 0; i < KK; i++) {        // R_row_i' = (R_row_i @ E2) * g
        float acc[KK];
        #pragma unroll
        for (int j = 0; j < KK; j++) acc[j] = R[i*KK] * e2[j];
        #pragma unroll
        for (int k = 1; k < KK; k++)
          #pragma unroll
          for (int j = 0; j < KK; j++) acc[j] = fmaf(R[i*KK + k], e2[k*KK + j], acc[j]);
        #pragma unroll
        for (int j = 0; j < KK; j++) R[i*KK + j] = acc[j] * g[j];
      }
      if ((cnt & 3) == 0) {
        #pragma unroll
        for (int i = 0; i < KK; i++) {
          float mm = R[i*KK];
          #pragma unroll
          for (int j = 1; j < KK; j++) mm = fmaxf(mm, R[i*KK + j]);
          int ex = (int)((__float_as_uint(mm) >> 23) & 255) - 127;
          float scl = __uint_as_float((unsigned)(127 - ex) << 23);
          Lr[i] += (float)ex;
          #pragma unroll
          for (int j = 0; j < KK; j++) R[i*KK + j] *= scl;
        }
      }
    }
    wsS[c * BB + b] = sc; wsC[c * BB + b] = cnt;
    if (cnt > 0) {
      float* P = wsP + ((size_t)(c - 1) * BB + b) * 49;
      #pragma unroll
      for (int i = 0; i < KK; i++)
        #pragma unroll
        for (int j = 0; j < KK; j++) P[i*KK + j] = Lr[i] + flog2(R[i*KK + j]);
    }
  }
}

// Phase 2: one wave per b. Combine alpha with chunk matrices (lane j owns state j),
// finish logZ, score terms, mean-reduce into out.
__global__ __launch_bounds__(256) void crf_p2(
    const float* __restrict__ em, const int* __restrict__ tgs,
    const float* __restrict__ stt, const float* __restrict__ ent,
    const float* __restrict__ wsA, const float* __restrict__ wsP,
    const float* __restrict__ wsS, const int* __restrict__ wsC,
    float* __restrict__ out)
{
  const float L2E = 1.44269504088896340736f;
  const float LN2 = 0.69314718055994530942f;
  __shared__ float sm[4];
  int w = threadIdx.x >> 6, lane = threadIdx.x & 63;
  int b = blockIdx.x * 4 + w;

  int cntv = 0; float scv = 0.f;
  if (lane < NC) { cntv = wsC[lane * BB + b]; scv = wsS[lane * BB + b]; }
  int len = cntv; float ssum = scv;
  #pragma unroll
  for (int o = 1; o < 64; o <<= 1) { len += __shfl_xor(len, o); ssum += __shfl_xor(ssum, o); }

  float A = (lane < KK) ? wsA[b * 8 + lane] : -1e30f;
  int j = (lane < KK) ? lane : 0;
  for (int c2 = 1; c2 < NC; c2++) {
    int cc = __shfl(cntv, c2);       // uniform across wave
    if (cc == 0) break;              // prefix mask -> rest are identity
    const float* P = wsP + ((size_t)(c2 - 1) * BB + b) * 49;
    float v[KK];
    #pragma unroll
    for (int i = 0; i < KK; i++) v[i] = __shfl(A, i) + P[i*KK + j];
    float m = v[0];
    #pragma unroll
    for (int i = 1; i < KK; i++) m = fmaxf(m, v[i]);
    float s = 0.f;
    #pragma unroll
    for (int i = 0; i < KK; i++) s += fexp2(v[i] - m);
    A = m + flog2(s);
  }
  // logZ = ln2 * LSE2_j(A_j + end_j*log2e)
  float x = (lane < KK) ? A + ent[lane] * L2E : -1e30f;
  float mx = x;
  #pragma unroll
  for (int o = 1; o < 8; o <<= 1) mx = fmaxf(mx, __shfl_xor(mx, o));
  float s = fexp2(x - mx);
  #pragma unroll
  for (int o = 1; o < 8; o <<= 1) s += __shfl_xor(s, o);

  if (lane == 0) {
    float logz = LN2 * (mx + flog2(s));
    int t0g = tgs[b * TT];
    float score = stt[t0g] + em[(size_t)b * TT * KK + t0g] + ssum
                + ent[tgs[b * TT + len - 1]];
    sm[w] = (logz - score) * (1.0f / BB);
  }
  __syncthreads();
  if (threadIdx.x == 0) atomicAdd(out, sm[0] + sm[1] + sm[2] + sm[3]);
}

extern "C" void kernel_launch(void* const* d_in, const int* in_sizes, int n_in,
                              void* d_out, int out_size, void* d_ws, size_t ws_size,
                              hipStream_t stream) {
  const float* em  = (const float*)d_in[0];
  const int*   msk = (const int*)d_in[1];
  const int*   tgs = (const int*)d_in[2];
  const float* trn = (const float*)d_in[3];
  const float* stt = (const float*)d_in[4];
  const float* ent = (const float*)d_in[5];
  float* out = (float*)d_out;

  float* wsA = (float*)d_ws;                         // BB*8
  float* wsP = wsA + (size_t)BB * 8;                 // (NC-1)*BB*49
  float* wsS = wsP + (size_t)(NC - 1) * BB * 49;     // NC*BB
  int*   wsC = (int*)(wsS + (size_t)NC * BB);        // NC*BB

  hipMemsetAsync(out, 0, sizeof(float), stream);
  hipLaunchKernelGGL(crf_p1, dim3(BB * NC / 256), dim3(256), 0, stream,
                     em, msk, tgs, trn, stt, wsA, wsP, wsS, wsC);
  hipLaunchKernelGGL(crf_p2, dim3(BB / 4), dim3(256), 0, stream,
                     em, tgs, stt, ent, wsA, wsP, wsS, wsC, out);
}